// Round 11
// baseline (1126.540 us; speedup 1.0000x reference)
//
#include <hip/hip_runtime.h>
#include <stdint.h>

// BitNet b1.58 column-parallel linear:
//   y[m,n] = (sum_k qx[m,k]*qw[n,k]) * inv_sx[m] * inv_sw + bias[n]
// M=8192 (B*S), N=16384 (D_OUT), K=4096 (D_IN)

#define M_ROWS 8192
#define N_COLS 16384
#define K_DIM  4096
#define NT     (K_DIM / 64)   // 64 K-steps of 64 bytes

typedef int v4i __attribute__((ext_vector_type(4)));

// ---------------- workspace layout ----------------
#define WS_PARTIALS 0
#define WS_PARAMS   8192
#define WS_INVSX    8448
#define WS_QX       41216
#define WS_QW       (41216 + 33554432)
#define WS_NEED     ((size_t)WS_QW + 67108864)

// ---------------- activation quant: per-row int8 absmax ----------------
__device__ __forceinline__ int quant_act1(float v, float s) {
    float q = rintf(v * s);               // round-half-even, matches jnp.round
    q = fminf(127.0f, fmaxf(-128.0f, q));
    return (int)q;
}

__global__ __launch_bounds__(256) void act_quant_kernel(const float* __restrict__ x,
                                                        int8_t* __restrict__ qx,
                                                        float* __restrict__ inv_sx) {
    const int row = blockIdx.x;
    const int t = threadIdx.x;
    const float4* xr = (const float4*)(x + (size_t)row * K_DIM);

    float4 v[4];
    float m = 0.0f;
#pragma unroll
    for (int i = 0; i < 4; ++i) {
        v[i] = xr[t + 256 * i];
        m = fmaxf(m, fmaxf(fmaxf(fabsf(v[i].x), fabsf(v[i].y)),
                           fmaxf(fabsf(v[i].z), fabsf(v[i].w))));
    }
#pragma unroll
    for (int off = 32; off > 0; off >>= 1) m = fmaxf(m, __shfl_xor(m, off));
    __shared__ float wm[4];
    if ((t & 63) == 0) wm[t >> 6] = m;
    __syncthreads();
    m = fmaxf(fmaxf(wm[0], wm[1]), fmaxf(wm[2], wm[3]));
    m = fmaxf(m, 1e-5f);                  // clip(max, EPS)
    const float scale = 127.0f / m;
    if (t == 0) inv_sx[row] = 1.0f / scale;

    int* qr = (int*)(qx + (size_t)row * K_DIM);
#pragma unroll
    for (int i = 0; i < 4; ++i) {
        int b0 = quant_act1(v[i].x, scale) & 255;
        int b1 = quant_act1(v[i].y, scale) & 255;
        int b2 = quant_act1(v[i].z, scale) & 255;
        int b3 = quant_act1(v[i].w, scale) & 255;
        qr[t + 256 * i] = b0 | (b1 << 8) | (b2 << 16) | (b3 << 24);
    }
}

// ---------------- weight abs-sum (deterministic two-stage) ----------------
__global__ __launch_bounds__(256) void wabs_partial_kernel(const float* __restrict__ w,
                                                           float* __restrict__ partials) {
    const int t = threadIdx.x;
    const size_t base = (size_t)blockIdx.x * 8192;   // float4 units
    const float4* w4 = (const float4*)w;
    float s = 0.0f;
#pragma unroll 8
    for (int i = 0; i < 32; ++i) {
        float4 v = w4[base + (size_t)i * 256 + t];
        s += fabsf(v.x) + fabsf(v.y) + fabsf(v.z) + fabsf(v.w);
    }
#pragma unroll
    for (int off = 32; off > 0; off >>= 1) s += __shfl_xor(s, off);
    __shared__ float wp[4];
    if ((t & 63) == 0) wp[t >> 6] = s;
    __syncthreads();
    if (t == 0) partials[blockIdx.x] = (wp[0] + wp[1]) + (wp[2] + wp[3]);
}

__global__ __launch_bounds__(256) void wfinal_kernel(const float* __restrict__ partials,
                                                     float* __restrict__ params) {
    __shared__ double sh[256];
    const int t = threadIdx.x;
    double s = 0.0;
    for (int i = t; i < 2048; i += 256) s += (double)partials[i];
    sh[t] = s;
    __syncthreads();
    for (int off = 128; off > 0; off >>= 1) {
        if (t < off) sh[t] += sh[t + off];
        __syncthreads();
    }
    if (t == 0) {
        float mean = (float)(sh[0] / 67108864.0);
        mean = fmaxf(mean, 1e-5f);        // clip(mean, EPS)
        float scale = 1.0f / mean;        // scale_w
        params[0] = scale;
        params[1] = 1.0f / scale;         // inv_sw
    }
}

// ---------------- weight quant: per-tensor ternary ----------------
__device__ __forceinline__ int quant_w1(float v, float s) {
    float q = rintf(v * s);
    q = fminf(1.0f, fmaxf(-1.0f, q));
    return (int)q;
}

__global__ __launch_bounds__(256) void w_quant_kernel(const float* __restrict__ w,
                                                      int8_t* __restrict__ qw,
                                                      const float* __restrict__ params) {
    const float scale = params[0];
    const int stride = gridDim.x * 256;
    const float4* w4 = (const float4*)w;
    int* q4 = (int*)qw;
    for (int g = blockIdx.x * 256 + threadIdx.x; g < 16777216; g += stride) {
        float4 v = w4[g];
        int b0 = quant_w1(v.x, scale) & 255;
        int b1 = quant_w1(v.y, scale) & 255;
        int b2 = quant_w1(v.z, scale) & 255;
        int b3 = quant_w1(v.w, scale) & 255;
        q4[g] = b0 | (b1 << 8) | (b2 << 16) | (b3 << 24);
    }
}

// ---------------- int8 GEMM: 256x128, 4 waves, A-only LDS ring, B direct to registers --
// R9 structure minus B's LDS round-trip: B fragments load global->VGPR (bytes identical
// to the old LDS path: row rb, chunk ksub*16 + t*64), cutting the DS pipe per block-step
// from 12 reads + 6 writes to 8 reads + 4 writes; B traffic moves to the idle VMEM pipe
// (B panel 512KB, L2-resident via bm-fast XCD swizzle). LDS = 3 x 16KB (A only) -> 48KB,
// 2 blocks/CU (m114 overlap). 4 waves (2M x 2N), per-wave 128x64, mfma_i32_16x16x64_i8.
// vmcnt ledger (4 loads per BL / per AG): steady queue [BL(t),AG(t+1),BL(t+1),AG(t+2)];
// vm8 at step t proves BL(t)+AG(t+1); barrier publishes slot (t+1)%3. B regs E/O
// double-buffered with static names (rule #20); 6-step unrolled period (slot x parity).
// A staging swizzle + aoff ds_read pattern unchanged (rounds 1-9: 0 bank conflicts).
__global__ __launch_bounds__(256, 2) void gemm_i8_kernel(const int8_t* __restrict__ qx,
                                                         const int8_t* __restrict__ qw,
                                                         const float* __restrict__ inv_sx,
                                                         const float* __restrict__ params,
                                                         const float* __restrict__ bias,
                                                         float* __restrict__ y) {
    __shared__ __align__(16) int8_t lds[3][16384];   // A[256][64] per slot
    int8_t* L = &lds[0][0];

    const int tid = threadIdx.x;
    const int lane = tid & 63;
    const int w = tid >> 6;           // wave 0..3
    const int wr = w >> 1;            // 0..1  (M half)
    const int wc = w & 1;             // 0..1  (N half)
    const int wbase = w * 1024;       // wave-uniform LDS staging base

    // XCD-aware bijective swizzle, bm-FAST: consecutive blocks share the B panel (L2)
    const int bid = blockIdx.x;
    const int swz = (bid & 7) * 512 + (bid >> 3);
    const int bm = swz & 31;          // 32 m-blocks (fast)
    const int bn = swz >> 5;          // 128 n-blocks

    const size_t arow0 = (size_t)bm * 256;
    const size_t bcol0 = (size_t)bn * 128;

    // A staging: 1024 chunks of 16B per slot (4/thread, row stride 64), swizzled source
    const int r0 = tid >> 2;                       // 0..63
    const int kc0 = (tid & 3) ^ ((r0 >> 1) & 3);   // swizzled k-slot (involution)
    const int8_t* gA = qx + (arow0 + r0) * K_DIM + kc0 * 16;

    const int ksub = lane >> 4;       // 16B k-chunk 0..3
    const int lrow = lane & 15;

    // B register-load base: row (bcol0 + wc*64 + lrow), chunk ksub*16; step adds t*64
    const int8_t* gBr = qw + (bcol0 + (size_t)(wc * 64 + lrow)) * K_DIM + ksub * 16;

#define GLD(g, l)                                                                        \
    __builtin_amdgcn_global_load_lds((const __attribute__((address_space(1))) void*)(g), \
                                     (__attribute__((address_space(3))) void*)(l), 16, 0, 0)

// stage A of K-step ks into slot S (4 x 16B per thread)
#define AG(ks, S)                                                                        \
    do {                                                                                 \
        const size_t _o = (size_t)(ks) * 64;                                             \
        _Pragma("unroll") for (int _g = 0; _g < 4; ++_g)                                 \
            GLD(gA + _o + (size_t)_g * (64 * K_DIM),                                     \
                L + (S) * 16384 + _g * 4096 + wbase);                                    \
    } while (0)

// load B fragments of K-step tt into register set DST (4 x dwordx4 per lane)
#define BL(DST, tt)                                                                      \
    do {                                                                                 \
        _Pragma("unroll") for (int _j = 0; _j < 4; ++_j)                                 \
            DST[_j] = *(const v4i*)(gBr + (size_t)(tt) * 64 + (size_t)_j * (16 * K_DIM)); \
    } while (0)

    // A fragment ds_read offsets (within one 16KB slot) — verified pattern, 0 conflicts
    int aoff[8];
#pragma unroll
    for (int i = 0; i < 8; ++i) {
        int ra = wr * 128 + i * 16 + lrow;
        aoff[i] = ra * 64 + ((ksub ^ ((ra >> 1) & 3)) << 4);
    }

    v4i acc[8][4];
#pragma unroll
    for (int i = 0; i < 8; ++i)
#pragma unroll
        for (int j = 0; j < 4; ++j) acc[i][j] = (v4i){0, 0, 0, 0};

    v4i bE[4], bO[4];

#define BARR()                                                                 \
    do {                                                                       \
        __builtin_amdgcn_s_barrier();                                          \
        __builtin_amdgcn_sched_barrier(0);                                     \
    } while (0)
#define VM(NSTR) asm volatile("s_waitcnt vmcnt(" NSTR ")" ::: "memory")

// One K-step: B(t+1)->BN regs, stage A(t+2), 8 a ds_reads slot CS, 32 MFMA with BC,
// counted vmcnt, barrier.
#define STEP(CS, BC, BN, TBL, TAG, SAG, DO_BL, DO_AG, VMSTMT, DOBAR)           \
    do {                                                                       \
        if (DO_BL) BL(BN, TBL);                                                \
        if (DO_AG) AG(TAG, SAG);                                               \
        const int8_t* _p = L + (CS) * 16384;                                   \
        v4i a[8];                                                              \
        _Pragma("unroll") for (int _i = 0; _i < 8; ++_i)                       \
            a[_i] = *(const v4i*)(_p + aoff[_i]);                              \
        __builtin_amdgcn_s_setprio(1);                                         \
        _Pragma("unroll") for (int _i = 0; _i < 8; ++_i)                       \
            _Pragma("unroll") for (int _j = 0; _j < 4; ++_j)                   \
                acc[_i][_j] = __builtin_amdgcn_mfma_i32_16x16x64_i8(           \
                    a[_i], BC[_j], acc[_i][_j], 0, 0, 0);                      \
        __builtin_amdgcn_s_setprio(0);                                         \
        VMSTMT;                                                                \
        if (DOBAR) BARR();                                                     \
    } while (0)

    // prologue: B(0)->bE, stage A(0)->s0, A(1)->s1; vm4 proves BL0+AG0; publish s0
    BL(bE, 0);
    AG(0, 0);
    AG(1, 1);
    VM("4");
    BARR();

    // main loop: 10 iters x 6 steps (t=0..59); slot=t%3, parity E(even t)/O(odd t)
#pragma unroll 1
    for (int j = 0; j < 10; ++j) {
        const int tb = 6 * j;
        STEP(0, bE, bO, tb + 1, tb + 2, 2, 1, 1, VM("8"), 1);
        STEP(1, bO, bE, tb + 2, tb + 3, 0, 1, 1, VM("8"), 1);
        STEP(2, bE, bO, tb + 3, tb + 4, 1, 1, 1, VM("8"), 1);
        STEP(0, bO, bE, tb + 4, tb + 5, 2, 1, 1, VM("8"), 1);
        STEP(1, bE, bO, tb + 5, tb + 6, 0, 1, 1, VM("8"), 1);
        STEP(2, bO, bE, tb + 6, tb + 7, 1, 1, 1, VM("8"), 1);
    }
    // tail: t=60..63
    STEP(0, bE, bO, 61, 62, 2, 1, 1, VM("8"), 1);       // t=60: proves AG61
    STEP(1, bO, bE, 62, 63, 0, 1, 1, VM("8"), 1);       // t=61: proves AG62
    STEP(2, bE, bO, 63, 0, 0, 1, 0, VM("4"), 1);        // t=62: proves AG63
    STEP(0, bO, bE, 0, 0, 0, 0, 0, (void)0, 0);         // t=63 (compiler drains bO dep)

    // epilogue: y = acc * inv_sx[row] * inv_sw + bias[col]  (verified 16x16 C/D layout)
    const float invsw = params[1];
    const int rl = (lane >> 4) * 4;
#pragma unroll
    for (int i = 0; i < 8; ++i) {
        const int grow_base = (int)arow0 + wr * 128 + i * 16 + rl;
        float isx[4];
#pragma unroll
        for (int r = 0; r < 4; ++r) isx[r] = inv_sx[grow_base + r] * invsw;
#pragma unroll
        for (int j = 0; j < 4; ++j) {
            const int gcol = (int)bcol0 + wc * 64 + j * 16 + lrow;
            const float bb = bias[gcol];
#pragma unroll
            for (int r = 0; r < 4; ++r) {
                y[(size_t)(grow_base + r) * N_COLS + gcol] =
                    (float)acc[i][j][r] * isx[r] + bb;
            }
        }
    }
#undef GLD
#undef AG
#undef BL
#undef BARR
#undef VM
#undef STEP
}

// ---------------- launch ----------------
extern "C" void kernel_launch(void* const* d_in, const int* in_sizes, int n_in,
                              void* d_out, int out_size, void* d_ws, size_t ws_size,
                              hipStream_t stream) {
    const float* x    = (const float*)d_in[0];
    const float* wt   = (const float*)d_in[1];
    const float* bias = (const float*)d_in[2];
    float* y = (float*)d_out;

    if (ws_size < WS_NEED) return;

    char* ws = (char*)d_ws;
    float* partials = (float*)(ws + WS_PARTIALS);
    float* params   = (float*)(ws + WS_PARAMS);
    float* inv_sx   = (float*)(ws + WS_INVSX);
    int8_t* qx = (int8_t*)(ws + WS_QX);
    int8_t* qw = (int8_t*)(ws + WS_QW);

    hipLaunchKernelGGL(act_quant_kernel,   dim3(8192), dim3(256), 0, stream, x, qx, inv_sx);
    hipLaunchKernelGGL(wabs_partial_kernel,dim3(2048), dim3(256), 0, stream, wt, partials);
    hipLaunchKernelGGL(wfinal_kernel,      dim3(1),    dim3(256), 0, stream, partials, params);
    hipLaunchKernelGGL(w_quant_kernel,     dim3(4096), dim3(256), 0, stream, wt, qw, params);
    hipLaunchKernelGGL(gemm_i8_kernel,     dim3(4096), dim3(256), 0, stream,
                       qx, qw, inv_sx, params, bias, y);
}

// Round 12
// 884.760 us; speedup vs baseline: 1.2733x; 1.2733x over previous
//
#include <hip/hip_runtime.h>
#include <stdint.h>

// BitNet b1.58 column-parallel linear:
//   y[m,n] = (sum_k qx[m,k]*qw[n,k]) * inv_sx[m] * inv_sw + bias[n]
// M=8192 (B*S), N=16384 (D_OUT), K=4096 (D_IN)

#define M_ROWS 8192
#define N_COLS 16384
#define K_DIM  4096
#define NT     (K_DIM / 64)   // 64 K-steps of 64 bytes

typedef int v4i __attribute__((ext_vector_type(4)));

// ---------------- workspace layout ----------------
#define WS_PARTIALS 0
#define WS_PARAMS   8192
#define WS_INVSX    8448
#define WS_QX       41216
#define WS_QW       (41216 + 33554432)
#define WS_NEED     ((size_t)WS_QW + 67108864)

// ---------------- activation quant: per-row int8 absmax ----------------
__device__ __forceinline__ int quant_act1(float v, float s) {
    float q = rintf(v * s);               // round-half-even, matches jnp.round
    q = fminf(127.0f, fmaxf(-128.0f, q));
    return (int)q;
}

__global__ __launch_bounds__(256) void act_quant_kernel(const float* __restrict__ x,
                                                        int8_t* __restrict__ qx,
                                                        float* __restrict__ inv_sx) {
    const int row = blockIdx.x;
    const int t = threadIdx.x;
    const float4* xr = (const float4*)(x + (size_t)row * K_DIM);

    float4 v[4];
    float m = 0.0f;
#pragma unroll
    for (int i = 0; i < 4; ++i) {
        v[i] = xr[t + 256 * i];
        m = fmaxf(m, fmaxf(fmaxf(fabsf(v[i].x), fabsf(v[i].y)),
                           fmaxf(fabsf(v[i].z), fabsf(v[i].w))));
    }
#pragma unroll
    for (int off = 32; off > 0; off >>= 1) m = fmaxf(m, __shfl_xor(m, off));
    __shared__ float wm[4];
    if ((t & 63) == 0) wm[t >> 6] = m;
    __syncthreads();
    m = fmaxf(fmaxf(wm[0], wm[1]), fmaxf(wm[2], wm[3]));
    m = fmaxf(m, 1e-5f);                  // clip(max, EPS)
    const float scale = 127.0f / m;
    if (t == 0) inv_sx[row] = 1.0f / scale;

    int* qr = (int*)(qx + (size_t)row * K_DIM);
#pragma unroll
    for (int i = 0; i < 4; ++i) {
        int b0 = quant_act1(v[i].x, scale) & 255;
        int b1 = quant_act1(v[i].y, scale) & 255;
        int b2 = quant_act1(v[i].z, scale) & 255;
        int b3 = quant_act1(v[i].w, scale) & 255;
        qr[t + 256 * i] = b0 | (b1 << 8) | (b2 << 16) | (b3 << 24);
    }
}

// ---------------- weight abs-sum (deterministic two-stage) ----------------
__global__ __launch_bounds__(256) void wabs_partial_kernel(const float* __restrict__ w,
                                                           float* __restrict__ partials) {
    const int t = threadIdx.x;
    const size_t base = (size_t)blockIdx.x * 8192;   // float4 units
    const float4* w4 = (const float4*)w;
    float s = 0.0f;
#pragma unroll 8
    for (int i = 0; i < 32; ++i) {
        float4 v = w4[base + (size_t)i * 256 + t];
        s += fabsf(v.x) + fabsf(v.y) + fabsf(v.z) + fabsf(v.w);
    }
#pragma unroll
    for (int off = 32; off > 0; off >>= 1) s += __shfl_xor(s, off);
    __shared__ float wp[4];
    if ((t & 63) == 0) wp[t >> 6] = s;
    __syncthreads();
    if (t == 0) partials[blockIdx.x] = (wp[0] + wp[1]) + (wp[2] + wp[3]);
}

__global__ __launch_bounds__(256) void wfinal_kernel(const float* __restrict__ partials,
                                                     float* __restrict__ params) {
    __shared__ double sh[256];
    const int t = threadIdx.x;
    double s = 0.0;
    for (int i = t; i < 2048; i += 256) s += (double)partials[i];
    sh[t] = s;
    __syncthreads();
    for (int off = 128; off > 0; off >>= 1) {
        if (t < off) sh[t] += sh[t + off];
        __syncthreads();
    }
    if (t == 0) {
        float mean = (float)(sh[0] / 67108864.0);
        mean = fmaxf(mean, 1e-5f);        // clip(mean, EPS)
        float scale = 1.0f / mean;        // scale_w
        params[0] = scale;
        params[1] = 1.0f / scale;         // inv_sw
    }
}

// ---------------- weight quant: per-tensor ternary ----------------
__device__ __forceinline__ int quant_w1(float v, float s) {
    float q = rintf(v * s);
    q = fminf(1.0f, fmaxf(-1.0f, q));
    return (int)q;
}

__global__ __launch_bounds__(256) void w_quant_kernel(const float* __restrict__ w,
                                                      int8_t* __restrict__ qw,
                                                      const float* __restrict__ params) {
    const float scale = params[0];
    const int stride = gridDim.x * 256;
    const float4* w4 = (const float4*)w;
    int* q4 = (int*)qw;
    for (int g = blockIdx.x * 256 + threadIdx.x; g < 16777216; g += stride) {
        float4 v = w4[g];
        int b0 = quant_w1(v.x, scale) & 255;
        int b1 = quant_w1(v.y, scale) & 255;
        int b2 = quant_w1(v.z, scale) & 255;
        int b3 = quant_w1(v.w, scale) & 255;
        q4[g] = b0 | (b1 << 8) | (b2 << 16) | (b3 << 24);
    }
}

// ---------------- int8 GEMM: 128x128 tile, 4 waves, 3-slot ring, 3 BLOCKS/CU ----
// R9's proven schedule at smaller accumulator scale to buy a 3rd co-resident block:
// blocks desync naturally and feed the MFMA pipe while siblings are in their read/
// barrier phase (the only lever that moved MfmaUtil: R8 1blk 39% -> R9 2blk 43.6%).
// Per block: acc 64 AGPR + ~100 VGPR = ~164 unified -> 12 waves/CU fit (2048/164);
// LDS ring-3 x 16KB = 48KB/block -> 3 blocks = 144KB <= 160KB.
// 4 waves (2M x 2N), per-wave 64x64, mfma_i32_16x16x64_i8 (verified layout).
// 3-slot ring (slot = t%3), stage-2-ahead, 4 GLD/thread/step (2 A + 2 B).
// Per step t: { 8 ds_read slot t%3 | GLD4(t+2 -> (t+2)%3) | 16 MFMA |
//              vmcnt(4) [proves K(t+1)] | s_barrier [publishes slot (t+1)%3] }.
// Slot-overwrite safety: GLD(t+2) targets slot (t-1)%3 whose reads drained before the
// end-of-(t-1) barrier (MFMA reg deps force lgkm completion pre-barrier). (R9 logic.)
// 16B-chunk XOR swizzle on global source + ds_read addr (rounds 1-10: 0 conflicts).
__global__ __launch_bounds__(256, 3) void gemm_i8_kernel(const int8_t* __restrict__ qx,
                                                         const int8_t* __restrict__ qw,
                                                         const float* __restrict__ inv_sx,
                                                         const float* __restrict__ params,
                                                         const float* __restrict__ bias,
                                                         float* __restrict__ y) {
    __shared__ __align__(16) int8_t lds[3][16384];   // per slot: A[128][64] + B[128][64]
    int8_t* L = &lds[0][0];

    const int tid = threadIdx.x;
    const int lane = tid & 63;
    const int w = tid >> 6;           // wave 0..3
    const int wr = w >> 1;            // 0..1  (M half)
    const int wc = w & 1;             // 0..1  (N half)

    // XCD-aware bijective swizzle: 8192 blocks, 8 XCDs; bn-fast (share A panel in L2)
    const int bid = blockIdx.x;
    const int swz = (bid & 7) * 1024 + (bid >> 3);
    const int bn = swz & 127;         // 128 n-blocks (fast)
    const int bm = swz >> 7;          // 64 m-blocks

    const size_t arow0 = (size_t)bm * 128;
    const size_t bcol0 = (size_t)bn * 128;

    // staging: A 512 chunks of 16B (2/thread, rows r0 and r0+64), B same
    const int r0 = tid >> 2;                       // 0..63
    const int kc0 = (tid & 3) ^ ((r0 >> 1) & 3);   // swizzled k-slot (involution)
    const int8_t* gA = qx + (arow0 + r0) * K_DIM + kc0 * 16;
    const int8_t* gB = qw + (bcol0 + r0) * K_DIM + kc0 * 16;

#define GLD(g, l)                                                                        \
    __builtin_amdgcn_global_load_lds((const __attribute__((address_space(1))) void*)(g), \
                                     (__attribute__((address_space(3))) void*)(l), 16, 0, 0)

// stage K-step ks into slot S: 2 A chunks + 2 B chunks per thread
#define GLD4(ks, S)                                                                      \
    do {                                                                                 \
        const size_t _o = (size_t)(ks) * 64;                                             \
        GLD(gA + _o, L + (S) * 16384 + tid * 16);                                        \
        GLD(gA + _o + (size_t)64 * K_DIM, L + (S) * 16384 + 4096 + tid * 16);            \
        GLD(gB + _o, L + (S) * 16384 + 8192 + tid * 16);                                 \
        GLD(gB + _o + (size_t)64 * K_DIM, L + (S) * 16384 + 12288 + tid * 16);           \
    } while (0)

    // fragment ds_read offsets (within one 16KB slot) — verified 16x16x64 layout
    const int ksub = lane >> 4;       // 16B k-chunk 0..3
    const int lrow = lane & 15;
    int aoff[4], boff[4];
#pragma unroll
    for (int i = 0; i < 4; ++i) {
        int ra = wr * 64 + i * 16 + lrow;
        aoff[i] = ra * 64 + ((ksub ^ ((ra >> 1) & 3)) << 4);
        int rb = wc * 64 + i * 16 + lrow;
        boff[i] = 8192 + rb * 64 + ((ksub ^ ((rb >> 1) & 3)) << 4);
    }

    v4i acc[4][4];
#pragma unroll
    for (int i = 0; i < 4; ++i)
#pragma unroll
        for (int j = 0; j < 4; ++j) acc[i][j] = (v4i){0, 0, 0, 0};

#define BARR()                                                                 \
    do {                                                                       \
        __builtin_amdgcn_s_barrier();                                          \
        __builtin_amdgcn_sched_barrier(0);                                     \
    } while (0)
#define VM(NSTR) asm volatile("s_waitcnt vmcnt(" NSTR ")" ::: "memory")

// One K-step: read 8 frags from slot CS, stage FKS (if STG), 16 MFMA, wait, barrier.
#define STEP(CS, FKS, FSL, STG, VMSTMT, DOBAR)                                 \
    do {                                                                       \
        const int8_t* _p = L + (CS) * 16384;                                   \
        v4i a[4], b[4];                                                        \
        _Pragma("unroll") for (int _i = 0; _i < 4; ++_i)                       \
            a[_i] = *(const v4i*)(_p + aoff[_i]);                              \
        _Pragma("unroll") for (int _j = 0; _j < 4; ++_j)                       \
            b[_j] = *(const v4i*)(_p + boff[_j]);                              \
        if (STG) GLD4(FKS, FSL);                                               \
        __builtin_amdgcn_s_setprio(1);                                         \
        _Pragma("unroll") for (int _i = 0; _i < 4; ++_i)                       \
            _Pragma("unroll") for (int _j = 0; _j < 4; ++_j)                   \
                acc[_i][_j] = __builtin_amdgcn_mfma_i32_16x16x64_i8(           \
                    a[_i], b[_j], acc[_i][_j], 0, 0, 0);                       \
        __builtin_amdgcn_s_setprio(0);                                         \
        VMSTMT;                                                                \
        if (DOBAR) BARR();                                                     \
    } while (0)

    // prologue: stage K0->s0, K1->s1; vmcnt(4) proves K0; barrier publishes s0
    GLD4(0, 0);
    GLD4(1, 1);
    VM("4");
    BARR();

    // main loop: j=0..19, K-steps 3j..3j+2 (t=0..59), staging t+2 (slots 2,0,1)
#pragma unroll 1
    for (int j = 0; j < 20; ++j) {
        const int tb = 3 * j;
        STEP(0, tb + 2, 2, 1, VM("4"), 1);   // t=3j: proves K(t+1)
        STEP(1, tb + 3, 0, 1, VM("4"), 1);
        STEP(2, tb + 4, 1, 1, VM("4"), 1);
    }
    // tail: t=60..63 (slots 0,1,2,0); K62 staged at t=60, K63 at t=61
    STEP(0, 62, 2, 1, VM("4"), 1);     // t=60: proves K61
    STEP(1, 63, 0, 1, VM("4"), 1);     // t=61: proves K62
    STEP(2, 0, 0, 0, VM("0"), 1);      // t=62: proves K63
    STEP(0, 0, 0, 0, (void)0, 0);      // t=63

    // epilogue: y = acc * inv_sx[row] * inv_sw + bias[col]  (verified 16x16 C/D layout)
    const float invsw = params[1];
    const int rl = (lane >> 4) * 4;
#pragma unroll
    for (int i = 0; i < 4; ++i) {
        const int grow_base = (int)arow0 + wr * 64 + i * 16 + rl;
        float isx[4];
#pragma unroll
        for (int r = 0; r < 4; ++r) isx[r] = inv_sx[grow_base + r] * invsw;
#pragma unroll
        for (int j = 0; j < 4; ++j) {
            const int gcol = (int)bcol0 + wc * 64 + j * 16 + lrow;
            const float bb = bias[gcol];
#pragma unroll
            for (int r = 0; r < 4; ++r) {
                y[(size_t)(grow_base + r) * N_COLS + gcol] =
                    (float)acc[i][j][r] * isx[r] + bb;
            }
        }
    }
#undef GLD
#undef GLD4
#undef BARR
#undef VM
#undef STEP
}

// ---------------- launch ----------------
extern "C" void kernel_launch(void* const* d_in, const int* in_sizes, int n_in,
                              void* d_out, int out_size, void* d_ws, size_t ws_size,
                              hipStream_t stream) {
    const float* x    = (const float*)d_in[0];
    const float* wt   = (const float*)d_in[1];
    const float* bias = (const float*)d_in[2];
    float* y = (float*)d_out;

    if (ws_size < WS_NEED) return;

    char* ws = (char*)d_ws;
    float* partials = (float*)(ws + WS_PARTIALS);
    float* params   = (float*)(ws + WS_PARAMS);
    float* inv_sx   = (float*)(ws + WS_INVSX);
    int8_t* qx = (int8_t*)(ws + WS_QX);
    int8_t* qw = (int8_t*)(ws + WS_QW);

    hipLaunchKernelGGL(act_quant_kernel,   dim3(8192), dim3(256), 0, stream, x, qx, inv_sx);
    hipLaunchKernelGGL(wabs_partial_kernel,dim3(2048), dim3(256), 0, stream, wt, partials);
    hipLaunchKernelGGL(wfinal_kernel,      dim3(1),    dim3(256), 0, stream, partials, params);
    hipLaunchKernelGGL(w_quant_kernel,     dim3(4096), dim3(256), 0, stream, wt, qw, params);
    hipLaunchKernelGGL(gemm_i8_kernel,     dim3(8192), dim3(256), 0, stream,
                       qx, qw, inv_sx, params, bias, y);
}